// Round 9
// baseline (5366.922 us; speedup 1.0000x reference)
//
#include <hip/hip_runtime.h>
#include <hip/hip_bf16.h>
#include <math.h>

using bf16 = __hip_bfloat16;

constexpr int CB = 4, CN = 1024, CD = 256, CH = 4, CFF = 2048;
constexpr int CNL = 2, CGL = 3, CK = 5, CBN = CB * CN;

// ---------------------------------------------------------------------------
// Tiled GEMM: C[m,n] = scale * sum_k A[m,k] * (TRANSB ? B[n,k] : B[k,n])
//             (+ bias[n]) (+= old C if ACCUM) (relu if RELU)
// Tile 128x64, K-step 16, 256 threads, 8x4 acc/thread (32 FMA per 3 LDS b128
// reads, vs 16/2 in the old 64x64 tile). All f32. Grid: (N/64, M/128, z).
// ---------------------------------------------------------------------------
template<bool TRANSB, bool RELU, bool ACCUM>
__global__ __launch_bounds__(256) void gemm_k(
    const float* __restrict__ A, int lda, long sAb, long sAz,
    const float* __restrict__ Bm, int ldb, long sBb, long sBz,
    float* __restrict__ C, int ldc, long sCb, long sCz,
    const float* __restrict__ bias, float scale, int K, int zdiv)
{
  __shared__ float As[16][128];   // [k][m]
  __shared__ float Bs[16][64];    // [k][n]
  const int t = threadIdx.x;
  const int z = blockIdx.z;
  const int zb = z / zdiv, zh = z - zb * zdiv;
  const float* Ap = A + (long)zb * sAb + (long)zh * sAz;
  const float* Bp = Bm + (long)zb * sBb + (long)zh * sBz;
  float* Cp = C + (long)zb * sCb + (long)zh * sCz;
  const int m0 = blockIdx.y * 128, n0 = blockIdx.x * 64;
  const int alr = t >> 1;           // A row 0..127
  const int alk = (t & 1) << 3;     // k offset 0 / 8 (two float4s -> full 64B/row)
  const int tr = t >> 4, tc = t & 15;
  const int mr = tr << 3, nc = tc << 2;   // 16x8 rows, 16x4 cols
  float acc[8][4] = {};
  for (int k0 = 0; k0 < K; k0 += 16) {
    float4 a1 = *(const float4*)&Ap[(long)(m0 + alr) * lda + k0 + alk];
    float4 a2 = *(const float4*)&Ap[(long)(m0 + alr) * lda + k0 + alk + 4];
    As[alk + 0][alr] = a1.x; As[alk + 1][alr] = a1.y;
    As[alk + 2][alr] = a1.z; As[alk + 3][alr] = a1.w;
    As[alk + 4][alr] = a2.x; As[alk + 5][alr] = a2.y;
    As[alk + 6][alr] = a2.z; As[alk + 7][alr] = a2.w;
    if (TRANSB) {
      const int blr = t >> 2, blk = (t & 3) << 2;
      float4 bv = *(const float4*)&Bp[(long)(n0 + blr) * ldb + k0 + blk];
      Bs[blk + 0][blr] = bv.x; Bs[blk + 1][blr] = bv.y;
      Bs[blk + 2][blr] = bv.z; Bs[blk + 3][blr] = bv.w;
    } else {
      const int bk = t >> 4, bn2 = (t & 15) << 2;
      float4 bv = *(const float4*)&Bp[(long)(k0 + bk) * ldb + n0 + bn2];
      Bs[bk][bn2 + 0] = bv.x; Bs[bk][bn2 + 1] = bv.y;
      Bs[bk][bn2 + 2] = bv.z; Bs[bk][bn2 + 3] = bv.w;
    }
    __syncthreads();
#pragma unroll
    for (int k = 0; k < 16; ++k) {
      float4 b = *(const float4*)&Bs[k][nc];
      float4 al = *(const float4*)&As[k][mr];
      float4 ah = *(const float4*)&As[k][mr + 4];
      float a8[8] = {al.x, al.y, al.z, al.w, ah.x, ah.y, ah.z, ah.w};
      float b4[4] = {b.x, b.y, b.z, b.w};
#pragma unroll
      for (int i = 0; i < 8; ++i)
#pragma unroll
        for (int j = 0; j < 4; ++j)
          acc[i][j] += a8[i] * b4[j];
    }
    __syncthreads();
  }
#pragma unroll
  for (int i = 0; i < 8; ++i) {
    float* crow = Cp + (long)(m0 + mr + i) * ldc + n0 + nc;
#pragma unroll
    for (int j = 0; j < 4; ++j) {
      float v = acc[i][j] * scale;
      if (bias) v += bias[n0 + nc + j];
      if (ACCUM) v += crow[j];
      if (RELU) v = fmaxf(v, 0.f);
      crow[j] = v;
    }
  }
}

// ---------------------------------------------------------------------------
// Fused flash-style attention for one (q-tile of 64, b*4+h). LDS 48 KiB.
// QKV: (4096 x 768) f32, q|k|v at col 0|256|512, head h at +h*64.
// O:   (4096 x 256) f32, head h at col h*64.  (validated vs naive impl, R6)
// ---------------------------------------------------------------------------
__global__ __launch_bounds__(256) void attn_k(const float* __restrict__ QKV,
                                              float* __restrict__ O)
{
  const int t = threadIdx.x;
  const int q0 = blockIdx.x * 64;
  const int b = blockIdx.y >> 2, h = blockIdx.y & 3;
  const float* base = QKV + (long)b * 786432;
  const int hc = h * 64;
  __shared__ float Qs[64][64];   // [d][m]
  __shared__ float KPs[64][64];  // S-phase: [d][n] = K^T;  PV-phase: [k][m] = P^T
  __shared__ float Vs[64][64];   // [k][d]
  const int ldr = t >> 2;
  const int ldc0 = (t & 3) * 16;
  {
    const float* qrow = base + (long)(q0 + ldr) * 768 + hc;
#pragma unroll
    for (int j = 0; j < 16; j += 4) {
      float4 v = *(const float4*)(qrow + ldc0 + j);
      Qs[ldc0 + j + 0][ldr] = v.x; Qs[ldc0 + j + 1][ldr] = v.y;
      Qs[ldc0 + j + 2][ldr] = v.z; Qs[ldc0 + j + 3][ldr] = v.w;
    }
  }
  const int mr = (t >> 4) << 2;
  const int nc = (t & 15) << 2;
  float mrow[4] = {-INFINITY, -INFINITY, -INFINITY, -INFINITY};
  float lrow[4] = {0.f, 0.f, 0.f, 0.f};
  float acc[4][4] = {};
  for (int kt = 0; kt < 16; ++kt) {
    __syncthreads();
    {
      const float* krow = base + (long)(kt * 64 + ldr) * 768 + 256 + hc;
      const float* vrow = base + (long)(kt * 64 + ldr) * 768 + 512 + hc;
#pragma unroll
      for (int j = 0; j < 16; j += 4) {
        float4 kv = *(const float4*)(krow + ldc0 + j);
        KPs[ldc0 + j + 0][ldr] = kv.x; KPs[ldc0 + j + 1][ldr] = kv.y;
        KPs[ldc0 + j + 2][ldr] = kv.z; KPs[ldc0 + j + 3][ldr] = kv.w;
        float4 vv = *(const float4*)(vrow + ldc0 + j);
        *(float4*)&Vs[ldr][ldc0 + j] = vv;
      }
    }
    __syncthreads();
    float s[4][4] = {};
#pragma unroll 8
    for (int d = 0; d < 64; ++d) {
      float4 a = *(const float4*)&Qs[d][mr];
      float4 bv = *(const float4*)&KPs[d][nc];
      s[0][0] += a.x * bv.x; s[0][1] += a.x * bv.y; s[0][2] += a.x * bv.z; s[0][3] += a.x * bv.w;
      s[1][0] += a.y * bv.x; s[1][1] += a.y * bv.y; s[1][2] += a.y * bv.z; s[1][3] += a.y * bv.w;
      s[2][0] += a.z * bv.x; s[2][1] += a.z * bv.y; s[2][2] += a.z * bv.z; s[2][3] += a.z * bv.w;
      s[3][0] += a.w * bv.x; s[3][1] += a.w * bv.y; s[3][2] += a.w * bv.z; s[3][3] += a.w * bv.w;
    }
#pragma unroll
    for (int i = 0; i < 4; ++i) {
#pragma unroll
      for (int j = 0; j < 4; ++j) s[i][j] *= 0.125f;
      float rm = fmaxf(fmaxf(s[i][0], s[i][1]), fmaxf(s[i][2], s[i][3]));
      rm = fmaxf(rm, __shfl_xor(rm, 1));
      rm = fmaxf(rm, __shfl_xor(rm, 2));
      rm = fmaxf(rm, __shfl_xor(rm, 4));
      rm = fmaxf(rm, __shfl_xor(rm, 8));
      float mn = fmaxf(mrow[i], rm);
      float corr = expf(mrow[i] - mn);
      float rs = 0.f;
#pragma unroll
      for (int j = 0; j < 4; ++j) {
        float p = expf(s[i][j] - mn);
        s[i][j] = p; rs += p;
      }
      rs += __shfl_xor(rs, 1);
      rs += __shfl_xor(rs, 2);
      rs += __shfl_xor(rs, 4);
      rs += __shfl_xor(rs, 8);
      lrow[i] = lrow[i] * corr + rs;
      mrow[i] = mn;
#pragma unroll
      for (int j = 0; j < 4; ++j) acc[i][j] *= corr;
    }
    __syncthreads();
#pragma unroll
    for (int i = 0; i < 4; ++i)
#pragma unroll
      for (int j = 0; j < 4; ++j)
        KPs[nc + j][mr + i] = s[i][j];
    __syncthreads();
#pragma unroll 8
    for (int k = 0; k < 64; ++k) {
      float4 p = *(const float4*)&KPs[k][mr];
      float4 v = *(const float4*)&Vs[k][nc];
      acc[0][0] += p.x * v.x; acc[0][1] += p.x * v.y; acc[0][2] += p.x * v.z; acc[0][3] += p.x * v.w;
      acc[1][0] += p.y * v.x; acc[1][1] += p.y * v.y; acc[1][2] += p.y * v.z; acc[1][3] += p.y * v.w;
      acc[2][0] += p.z * v.x; acc[2][1] += p.z * v.y; acc[2][2] += p.z * v.z; acc[2][3] += p.z * v.w;
      acc[3][0] += p.w * v.x; acc[3][1] += p.w * v.y; acc[3][2] += p.w * v.z; acc[3][3] += p.w * v.w;
    }
  }
#pragma unroll
  for (int i = 0; i < 4; ++i) {
    float inv = 1.f / lrow[i];
    float* orow = O + (long)(b * 1024 + q0 + mr + i) * 256 + hc + nc;
    orow[0] = acc[i][0] * inv; orow[1] = acc[i][1] * inv;
    orow[2] = acc[i][2] * inv; orow[3] = acc[i][3] * inv;
  }
}

// ---------------------------------------------------------------------------
// out = LN(x + y) * g + b   (rows of 256, one block per row) — f32 out
// ---------------------------------------------------------------------------
__global__ __launch_bounds__(256) void resln_k(
    const float* __restrict__ x, const float* __restrict__ y,
    const float* __restrict__ g, const float* __restrict__ be, float* __restrict__ out)
{
  const long row = blockIdx.x;
  const int t = threadIdx.x;
  float v = x[row * 256 + t] + y[row * 256 + t];
  float s = v;
#pragma unroll
  for (int o = 32; o > 0; o >>= 1) s += __shfl_xor(s, o);
  __shared__ float w1r[4];
  __shared__ float w2r[4];
  if ((t & 63) == 0) w1r[t >> 6] = s;
  __syncthreads();
  float mean = (w1r[0] + w1r[1] + w1r[2] + w1r[3]) * (1.f / 256.f);
  float d = v - mean;
  float q = d * d;
#pragma unroll
  for (int o = 32; o > 0; o >>= 1) q += __shfl_xor(q, o);
  if ((t & 63) == 0) w2r[t >> 6] = q;
  __syncthreads();
  float var = (w2r[0] + w2r[1] + w2r[2] + w2r[3]) * (1.f / 256.f);
  out[row * 256 + t] = d * (1.f / sqrtf(var + 1e-5f)) * g[t] + be[t];
}

// ---------------------------------------------------------------------------
// Fused beat encoder v2 (one block per (b,n)); writes e and masked em.
// Changes vs v1 (740us, 24% occ, 5.2e7 bank conflicts):
//  - no w2s LDS staging: conv weights are wave-uniform -> readfirstlane +
//    scalar (s_load) reads, L1-cached across blocks. LDS 59904 -> ~17.7 KB
//    => 8 blocks/CU (was 2).
//  - conv1 output stored even/odd split (o1e/o1o), so conv2's stride-2 lane
//    access becomes stride-1 => bank-conflict-free.
// ---------------------------------------------------------------------------
__global__ __launch_bounds__(256) void encoder_k(
    const float* __restrict__ beats, const float* __restrict__ rr,
    const float* __restrict__ c1w, const float* __restrict__ c1b,
    const float* __restrict__ c2w, const float* __restrict__ c2b,
    const float* __restrict__ fcw, const float* __restrict__ fcb,
    const float* __restrict__ mtok, const int* __restrict__ nmask,
    const float* __restrict__ vmask,
    float* __restrict__ e, float* __restrict__ em)
{
  const int bn = blockIdx.x;
  const int t = threadIdx.x;
  __shared__ float xin[256];
  __shared__ float o1e[32][64];   // conv1 out, even positions (l=2*i)
  __shared__ float o1o[32][64];   // conv1 out, odd positions  (l=2*i+1)
  __shared__ float pooled[66];
  xin[t] = beats[(long)bn * 256 + t];
  __syncthreads();
  // conv1: 32ch x 128L, stride2 pad2. c = idx>>7 is wave-uniform (idx is
  // 64-aligned with span 64, so no 128-boundary crossing within a wave).
  for (int r = 0; r < 16; ++r) {
    int idx = t + 256 * r;
    int c = idx >> 7, l = idx & 127;
    int cu = __builtin_amdgcn_readfirstlane(c);
    const float* w = c1w + cu * 5;
    float a = c1b[cu];
    int base = 2 * l - 2;
    if (base >= 0) a += xin[base] * w[0];
    if (base + 1 >= 0) a += xin[base + 1] * w[1];
    a += xin[base + 2] * w[2];
    a += xin[base + 3] * w[3];
    if (base + 4 < 256) a += xin[base + 4] * w[4];
    a = fmaxf(a, 0.f);
    if (l & 1) o1o[c][l >> 1] = a; else o1e[c][l >> 1] = a;
  }
  __syncthreads();
  // conv2 (64ch x 64L) + mean pool. c = (t>>6) + 4r exactly wave-uniform;
  // each wave handles one output channel's 64 positions (l = lane).
  // input pos for output l: 2l-2+u -> e[l-1], o[l-1], e[l], o[l], e[l+1].
  for (int r = 0; r < 16; ++r) {
    int idx = t + 256 * r;
    int c = idx >> 6, l = idx & 63;
    int cu = __builtin_amdgcn_readfirstlane(c);
    float a = c2b[cu];
    bool hm = (l > 0), hp = (l < 63);
    int lm = hm ? l - 1 : 0;
    int lp = hp ? l + 1 : 63;
    for (int ci = 0; ci < 32; ++ci) {
      const float* w = c2w + (cu * 32 + ci) * 5;
      float w0 = w[0], w1 = w[1], w2v = w[2], w3 = w[3], w4 = w[4];
      float e0 = o1e[ci][l], o0 = o1o[ci][l];
      float emv = o1e[ci][lm], omv = o1o[ci][lm];
      float epv = o1e[ci][lp];
      a += e0 * w2v + o0 * w3;
      if (hm) a += emv * w0 + omv * w1;
      if (hp) a += epv * w4;
    }
    a = fmaxf(a, 0.f);
#pragma unroll
    for (int o = 32; o > 0; o >>= 1) a += __shfl_xor(a, o);
    if ((t & 63) == 0) pooled[cu] = a * (1.f / 64.f);  // c unique per (wave,r)
  }
  if (t == 64) pooled[64] = rr[(long)bn * 2 + 0];
  if (t == 65) pooled[65] = rr[(long)bn * 2 + 1];
  __syncthreads();
  // fc(66 -> 256), one output per thread
  float a = fcb[t];
  for (int k = 0; k < 66; ++k) a += pooled[k] * fcw[t * 66 + k];
  e[(long)bn * 256 + t] = a;
  float mv = nmask[bn] ? mtok[t] : a;
  em[(long)bn * 256 + t] = mv * vmask[bn];
}

// ---------------------------------------------------------------------------
// Top-5 per sim row (ties -> lower index), union band {i-1,i+1}. One batch.
// ---------------------------------------------------------------------------
__global__ __launch_bounds__(256) void topk_k(const float* __restrict__ sim, int b,
    int* __restrict__ nbr, float* __restrict__ deg)
{
  const int i = blockIdx.x;
  const float* row = sim + (long)i * CN;
  const int t = threadIdx.x;
  float v[4]; int id[4];
  float4 rv = ((const float4*)row)[t];
  v[0] = rv.x; v[1] = rv.y; v[2] = rv.z; v[3] = rv.w;
#pragma unroll
  for (int j = 0; j < 4; ++j) id[j] = t * 4 + j;
  __shared__ float vr[256];
  __shared__ int ir[256];
  __shared__ int chosen[CK];
  for (int kk = 0; kk < CK; ++kk) {
    float bv = v[0]; int bi = id[0];
#pragma unroll
    for (int j = 1; j < 4; ++j)
      if (v[j] > bv || (v[j] == bv && id[j] < bi)) { bv = v[j]; bi = id[j]; }
    vr[t] = bv; ir[t] = bi;
    __syncthreads();
    for (int s2 = 128; s2 > 0; s2 >>= 1) {
      if (t < s2) {
        float ov = vr[t + s2]; int oi = ir[t + s2];
        if (ov > vr[t] || (ov == vr[t] && oi < ir[t])) { vr[t] = ov; ir[t] = oi; }
      }
      __syncthreads();
    }
    if (t == 0) chosen[kk] = ir[0];
    __syncthreads();
    int c = chosen[kk];
#pragma unroll
    for (int j = 0; j < 4; ++j) if (id[j] == c) v[j] = -INFINITY;
  }
  if (t == 0) {
    int list[CK + 2]; int cnt = 0;
    for (int kk = 0; kk < CK; ++kk) list[cnt++] = chosen[kk];
    if (i > 0) {
      bool found = false;
      for (int j = 0; j < CK; ++j) if (chosen[j] == i - 1) found = true;
      if (!found) list[cnt++] = i - 1;
    }
    if (i < CN - 1) {
      bool found = false;
      for (int j = 0; j < CK; ++j) if (chosen[j] == i + 1) found = true;
      if (!found) list[cnt++] = i + 1;
    }
    deg[(long)b * CN + i] = (float)cnt;
    for (int j = 0; j < 8; ++j)
      nbr[((long)b * CN + i) * 8 + j] = (j < cnt) ? list[j] : -1;
  }
}

// ---------------------------------------------------------------------------
// Sparse GNN aggregate: agg[i,:] = sum_{j in nbr(i)} x[j,:] / (deg + 1e-6)
// ---------------------------------------------------------------------------
__global__ __launch_bounds__(256) void agg_k(const float* __restrict__ x,
    const int* __restrict__ nbr, const float* __restrict__ deg, float* __restrict__ agg)
{
  const long row = blockIdx.x;
  const int t = threadIdx.x;
  const long bbase = (row >> 10) << 10;
  const int* nb = &nbr[row * 8];
  float s = 0.f;
  for (int j = 0; j < 8; ++j) {
    int n2 = nb[j];
    if (n2 >= 0) s += x[(bbase + n2) * 256 + t];
  }
  agg[row * 256 + t] = s / (deg[row] + 1e-6f);
}

// ---------------------------------------------------------------------------
// Bool-mask upload-layout detection + build.
// ---------------------------------------------------------------------------
__global__ void maskdetect_k(const unsigned char* __restrict__ p, int* __restrict__ flag) {
  int i = blockIdx.x * 256 + threadIdx.x;
  unsigned char c = p[i];
  int f = 0;
  if (c == 0x01) f |= 1;
  if (c == 0x3F || c == 0x80) f |= 2;
  if (c != 0 && (i & 3) == 1) f |= 4;
  if (c != 0 && ((i & 3) == 2 || (i & 3) == 3)) f |= 8;
  if (f) atomicOr(flag, f);
}
__global__ void maskbuild_k(const void* __restrict__ nm, const void* __restrict__ vm,
                            const int* __restrict__ flag, int* __restrict__ outm,
                            float* __restrict__ outv) {
  int i = blockIdx.x * 256 + threadIdx.x;
  int f = *flag;
  int layout;                                // 0=i32, 1=i8, 2=bf16, 3=f32
  if (f & 2) layout = (f & 4) ? 2 : 3;
  else if (f & (4 | 8)) layout = 1;
  else layout = 0;
  bool m, vv;
  if (layout == 1)      { m = ((const unsigned char*)nm)[i] != 0;  vv = ((const unsigned char*)vm)[i] != 0; }
  else if (layout == 0) { m = ((const int*)nm)[i] != 0;            vv = ((const int*)vm)[i] != 0; }
  else if (layout == 2) { m = ((const unsigned short*)nm)[i] != 0; vv = ((const unsigned short*)vm)[i] != 0; }
  else                  { m = ((const unsigned int*)nm)[i] != 0;   vv = ((const unsigned int*)vm)[i] != 0; }
  outm[i] = m ? 1 : 0;
  outv[i] = vv ? 1.f : 0.f;
}

// ---------------------------------------------------------------------------
// Host-side: post-norm transformer stack; final LN writes f32 to xfinal.
// ---------------------------------------------------------------------------
static void run_temporal(const float* x0, float* bufX, float* xfinal,
    const float* qkv_w, const float* qkv_b, const float* out_w, const float* out_b,
    const float* ln1g, const float* ln1b, const float* w1, const float* b1,
    const float* w2, const float* b2, const float* ln2g, const float* ln2b,
    float* F_QKV, float* F_H, float* F_O, float* F_T, hipStream_t stream)
{
  for (int l = 0; l < CNL; ++l) {
    const float* xs = (l == 0) ? x0 : bufX;
    // qkv = x @ qkv_w.T + qkv_b        (4096 x 768, K=256)
    gemm_k<true, false, false><<<dim3(12, 32, 1), 256, 0, stream>>>(
        xs, 256, 0, 0, qkv_w + (long)l * 768 * 256, 256, 0, 0,
        F_QKV, 768, 0, 0, qkv_b + l * 768, 1.f, 256, 1);
    // fused attention -> F_O
    attn_k<<<dim3(16, 16), 256, 0, stream>>>(F_QKV, F_O);
    // proj = O @ out_w.T + out_b       (4096 x 256)
    gemm_k<true, false, false><<<dim3(4, 32, 1), 256, 0, stream>>>(
        F_O, 256, 0, 0, out_w + (long)l * 65536, 256, 0, 0,
        F_T, 256, 0, 0, out_b + l * 256, 1.f, 256, 1);
    // x = LN(x + proj)
    resln_k<<<CBN, 256, 0, stream>>>(xs, F_T, ln1g + l * 256, ln1b + l * 256, bufX);
    // FFN in 4 chunks of 1024 rows (h reuses the dead QKV region)
    for (int c = 0; c < 4; ++c) {
      const float* xc = bufX + (long)c * 262144;
      gemm_k<true, true, false><<<dim3(32, 8, 1), 256, 0, stream>>>(
          xc, 256, 0, 0, w1 + (long)l * 2048 * 256, 256, 0, 0,
          F_H, 2048, 0, 0, b1 + l * 2048, 1.f, 256, 1);
      gemm_k<true, false, false><<<dim3(4, 8, 1), 256, 0, stream>>>(
          F_H, 2048, 0, 0, w2 + (long)l * 2048 * 256, 2048, 0, 0,
          F_T + (long)c * 262144, 256, 0, 0, b2 + l * 256, 1.f, 2048, 1);
    }
    // x = LN(x + h2)
    float* dst = (l < CNL - 1) ? bufX : xfinal;
    resln_k<<<CBN, 256, 0, stream>>>(bufX, F_T, ln2g + l * 256, ln2b + l * 256, dst);
  }
}

extern "C" void kernel_launch(void* const* d_in, const int* in_sizes, int n_in,
                              void* d_out, int out_size, void* d_ws, size_t ws_size,
                              hipStream_t stream)
{
  (void)in_sizes; (void)n_in; (void)out_size; (void)ws_size;
  const float* beats = (const float*)d_in[0];
  const float* rr    = (const float*)d_in[1];
  const void*  nmask = d_in[2];
  const void*  vmask = d_in[3];
  const float* c1w  = (const float*)d_in[4];
  const float* c1b  = (const float*)d_in[5];
  const float* c2w  = (const float*)d_in[6];
  const float* c2b  = (const float*)d_in[7];
  const float* fcw  = (const float*)d_in[8];
  const float* fcb  = (const float*)d_in[9];
  const float* mtok = (const float*)d_in[10];
  const float* qkv_w = (const float*)d_in[11];
  const float* qkv_b = (const float*)d_in[12];
  const float* out_w = (const float*)d_in[13];
  const float* out_b = (const float*)d_in[14];
  const float* ln1g = (const float*)d_in[15];
  const float* ln1b = (const float*)d_in[16];
  const float* w1   = (const float*)d_in[17];
  const float* b1   = (const float*)d_in[18];
  const float* w2   = (const float*)d_in[19];
  const float* b2   = (const float*)d_in[20];
  const float* ln2g = (const float*)d_in[21];
  const float* ln2b = (const float*)d_in[22];
  const float* gsw  = (const float*)d_in[23];
  const float* gsb  = (const float*)d_in[24];
  const float* gnw  = (const float*)d_in[25];
  const float* gnb  = (const float*)d_in[26];
  const float* dcw  = (const float*)d_in[27];
  const float* dcb  = (const float*)d_in[28];
  float* out = (float*)d_out;   // f32 output (reference returns float32)

  // ---- workspace layout (~32.3 MB of f32) ----
  float* W = (float*)d_ws;
  const long M1 = 1048576;
  float* F_X   = W + 0 * M1;    // current x
  float* F_E   = W + 1 * M1;    // encoder out / GNN ping-pong
  float* F_EM  = W + 2 * M1;    // masked encoder out / GNN agg
  float* F_QKV = W + 3 * M1;    // 4096x768 (3M); aliased: FFN h (2M), sim (1M)
  float* F_O   = W + 6 * M1;    // attn out
  float* F_T   = W + 7 * M1;    // proj / ffn2 tmp
  float* MISC  = W + 8 * M1;
  float* F_DEG = MISC;                    // 4096
  float* F_VAL = MISC + 4096;             // 4096
  int*   I_MASK = (int*)(MISC + 8192);    // 4096
  int*   I_NBR  = I_MASK + 4096;          // 4096*8
  int*   I_FLAG = I_NBR + 4096 * 8;       // 1
  float* F_H   = F_QKV;
  float* F_SIM = F_QKV;
  float* F_G2  = F_E;
  float* F_AGG = F_EM;

  // --- masks (layout-detected) ---
  hipMemsetAsync(I_FLAG, 0, 4, stream);
  maskdetect_k<<<16, 256, 0, stream>>>((const unsigned char*)nmask, I_FLAG);
  maskbuild_k<<<16, 256, 0, stream>>>(nmask, vmask, I_FLAG, I_MASK, F_VAL);

  // --- beat encoder -> e, em ---
  encoder_k<<<CBN, 256, 0, stream>>>(beats, rr, c1w, c1b, c2w, c2b, fcw, fcb, mtok,
                                     I_MASK, F_VAL, F_E, F_EM);

  // --- target branch: temporal(e) -> out[0:1M] (f32) ---
  run_temporal(F_E, F_X, out,
      qkv_w, qkv_b, out_w, out_b, ln1g, ln1b, w1, b1, w2, b2, ln2g, ln2b,
      F_QKV, F_H, F_O, F_T, stream);

  // --- masked branch: temporal(em) -> F_X (f32) ---
  run_temporal(F_EM, F_X, F_X,
      qkv_w, qkv_b, out_w, out_b, ln1g, ln1b, w1, b1, w2, b2, ln2g, ln2b,
      F_QKV, F_H, F_O, F_T, stream);

  // --- graph build (per batch): sim_b = x_b @ x_b^T, topk(5) + band ---
  for (int b = 0; b < CB; ++b) {
    gemm_k<true, false, false><<<dim3(16, 8, 1), 256, 0, stream>>>(
        F_X + (long)b * 262144, 256, 0, 0, F_X + (long)b * 262144, 256, 0, 0,
        F_SIM, 1024, 0, 0, nullptr, 1.f, 256, 1);
    topk_k<<<CN, 256, 0, stream>>>(F_SIM, b, I_NBR, F_DEG);
  }

  // --- GNN layers (sparse aggregate + 2 GEMMs each) ---
  float* cur = F_X; float* oth = F_G2;
  for (int l = 0; l < CGL; ++l) {
    agg_k<<<CBN, 256, 0, stream>>>(cur, I_NBR, F_DEG, F_AGG);
    gemm_k<true, false, false><<<dim3(4, 32, 1), 256, 0, stream>>>(
        cur, 256, 0, 0, gsw + (long)l * 65536, 256, 0, 0,
        oth, 256, 0, 0, gsb + l * 256, 1.f, 256, 1);
    gemm_k<true, false, true><<<dim3(4, 32, 1), 256, 0, stream>>>(
        F_AGG, 256, 0, 0, gnw + (long)l * 65536, 256, 0, 0,
        oth, 256, 0, 0, gnb + l * 256, 1.f, 256, 1);
    float* t2 = cur; cur = oth; oth = t2;
  }

  // --- decoder: recon = x @ dec_w.T + dec_b -> out[1M:2M] (f32) ---
  gemm_k<true, false, false><<<dim3(4, 32, 1), 256, 0, stream>>>(
      cur, 256, 0, 0, dcw, 256, 0, 0, out + M1, 256, 0, 0, dcb, 1.f, 256, 1);
}

// Round 10
// 1646.413 us; speedup vs baseline: 3.2598x; 3.2598x over previous
//
#include <hip/hip_runtime.h>
#include <hip/hip_bf16.h>
#include <math.h>

using bf16 = __hip_bfloat16;

constexpr int CB = 4, CN = 1024, CD = 256, CH = 4, CFF = 2048;
constexpr int CNL = 2, CGL = 3, CK = 5, CBN = CB * CN;

using bfrag = __attribute__((ext_vector_type(8))) short;   // 8 bf16 (4 VGPR)
using ffrag = __attribute__((ext_vector_type(4))) float;   // 4 f32 acc

__device__ __forceinline__ unsigned short f2b(float f) {   // f32->bf16 RNE
  union { float f; unsigned int u; } c; c.f = f;
  unsigned int u = c.u;
  return (unsigned short)((u + 0x7FFF + ((u >> 16) & 1)) >> 16);
}

// ---------------------------------------------------------------------------
// f32 tiled GEMM (proven R8 config): C = scale*A*(B or B^T) (+bias)(+=C)(relu)
// Tile 64x64, K-step 16, 256 threads, 4x4 acc/thread.
// ---------------------------------------------------------------------------
template<bool TRANSB, bool RELU, bool ACCUM>
__global__ __launch_bounds__(256) void gemm_k(
    const float* __restrict__ A, int lda, long sAb, long sAz,
    const float* __restrict__ Bm, int ldb, long sBb, long sBz,
    float* __restrict__ C, int ldc, long sCb, long sCz,
    const float* __restrict__ bias, float scale, int K, int zdiv)
{
  __shared__ float As[16][64];
  __shared__ float Bs[16][64];
  const int t = threadIdx.x;
  const int z = blockIdx.z;
  const int zb = z / zdiv, zh = z - zb * zdiv;
  const float* Ap = A + (long)zb * sAb + (long)zh * sAz;
  const float* Bp = Bm + (long)zb * sBb + (long)zh * sBz;
  float* Cp = C + (long)zb * sCb + (long)zh * sCz;
  const int m0 = blockIdx.y * 64, n0 = blockIdx.x * 64;
  const int lr = t >> 2;
  const int lk = (t & 3) << 2;
  const int mr = (t >> 4) << 2;
  const int nc = (t & 15) << 2;
  float acc[4][4] = {};
  for (int k0 = 0; k0 < K; k0 += 16) {
    float4 av = *(const float4*)&Ap[(long)(m0 + lr) * lda + k0 + lk];
    As[lk + 0][lr] = av.x; As[lk + 1][lr] = av.y;
    As[lk + 2][lr] = av.z; As[lk + 3][lr] = av.w;
    if (TRANSB) {
      float4 bv = *(const float4*)&Bp[(long)(n0 + lr) * ldb + k0 + lk];
      Bs[lk + 0][lr] = bv.x; Bs[lk + 1][lr] = bv.y;
      Bs[lk + 2][lr] = bv.z; Bs[lk + 3][lr] = bv.w;
    } else {
      const int bk = t >> 4, bn2 = (t & 15) << 2;
      float4 bv = *(const float4*)&Bp[(long)(k0 + bk) * ldb + n0 + bn2];
      Bs[bk][bn2 + 0] = bv.x; Bs[bk][bn2 + 1] = bv.y;
      Bs[bk][bn2 + 2] = bv.z; Bs[bk][bn2 + 3] = bv.w;
    }
    __syncthreads();
#pragma unroll
    for (int k = 0; k < 16; ++k) {
      float4 a = *(const float4*)&As[k][mr];
      float4 b = *(const float4*)&Bs[k][nc];
      acc[0][0] += a.x * b.x; acc[0][1] += a.x * b.y; acc[0][2] += a.x * b.z; acc[0][3] += a.x * b.w;
      acc[1][0] += a.y * b.x; acc[1][1] += a.y * b.y; acc[1][2] += a.y * b.z; acc[1][3] += a.y * b.w;
      acc[2][0] += a.z * b.x; acc[2][1] += a.z * b.y; acc[2][2] += a.z * b.z; acc[2][3] += a.z * b.w;
      acc[3][0] += a.w * b.x; acc[3][1] += a.w * b.y; acc[3][2] += a.w * b.z; acc[3][3] += a.w * b.w;
    }
    __syncthreads();
  }
#pragma unroll
  for (int i = 0; i < 4; ++i) {
    float* crow = Cp + (long)(m0 + mr + i) * ldc + n0 + nc;
#pragma unroll
    for (int j = 0; j < 4; ++j) {
      float v = acc[i][j] * scale;
      if (bias) v += bias[n0 + nc + j];
      if (ACCUM) v += crow[j];
      if (RELU) v = fmaxf(v, 0.f);
      crow[j] = v;
    }
  }
}

// ---------------------------------------------------------------------------
// bf16 MFMA GEMM (NEW): C[m,n] = sum_k A[m,k]*B[n,k] (+bias) (relu).
// f32 inputs rounded to bf16 (RNE) at LDS staging; f32 accumulate via
// v_mfma_f32_16x16x32_bf16. Tile 64x64, K-step 32, 4 waves; wave w owns rows
// [16w,16w+16), 4 col-tiles each. Fragment map (gfx950): A lane l holds
// A[l&15][(l>>4)*8+j]; B lane l holds B[(l>>4)*8+j][l&15] (= Bstored[l&15][k]
// for B^T); D: row=(l>>4)*4+r, col=l&15. KP=40 pad: 16B-aligned rows, <=2-way
// bank conflicts. Requires K % 32 == 0 (all call sites: 256/2048).
// ---------------------------------------------------------------------------
template<bool RELU>
__global__ __launch_bounds__(256) void bgemm_k(
    const float* __restrict__ A, int lda,
    const float* __restrict__ Bm, int ldb,
    float* __restrict__ C, int ldc,
    const float* __restrict__ bias, int K)
{
  constexpr int KP = 40;
  __shared__ unsigned short Asb[64 * KP];
  __shared__ unsigned short Bsb[64 * KP];
  const int t = threadIdx.x;
  const int m0 = blockIdx.y * 64, n0 = blockIdx.x * 64;
  const int srow = t >> 2, skk = (t & 3) << 3;   // staging: row, k-octet
  const int w = t >> 6, l = t & 63;
  const int lr = l & 15, lg = l >> 4;            // frag row-in-tile, k-group
  ffrag acc[4] = {};
  for (int k0 = 0; k0 < K; k0 += 32) {
    const float* arow = A + (long)(m0 + srow) * lda + k0 + skk;
    const float* brow = Bm + (long)(n0 + srow) * ldb + k0 + skk;
    float4 a1 = *(const float4*)(arow);
    float4 a2 = *(const float4*)(arow + 4);
    float4 b1 = *(const float4*)(brow);
    float4 b2 = *(const float4*)(brow + 4);
    bfrag ap, bp;
    ap[0] = (short)f2b(a1.x); ap[1] = (short)f2b(a1.y);
    ap[2] = (short)f2b(a1.z); ap[3] = (short)f2b(a1.w);
    ap[4] = (short)f2b(a2.x); ap[5] = (short)f2b(a2.y);
    ap[6] = (short)f2b(a2.z); ap[7] = (short)f2b(a2.w);
    bp[0] = (short)f2b(b1.x); bp[1] = (short)f2b(b1.y);
    bp[2] = (short)f2b(b1.z); bp[3] = (short)f2b(b1.w);
    bp[4] = (short)f2b(b2.x); bp[5] = (short)f2b(b2.y);
    bp[6] = (short)f2b(b2.z); bp[7] = (short)f2b(b2.w);
    __syncthreads();   // prev iter's fragment reads complete
    *(bfrag*)&Asb[srow * KP + skk] = ap;
    *(bfrag*)&Bsb[srow * KP + skk] = bp;
    __syncthreads();   // staged data visible
    bfrag af = *(const bfrag*)&Asb[(w * 16 + lr) * KP + lg * 8];
#pragma unroll
    for (int c = 0; c < 4; ++c) {
      bfrag bf = *(const bfrag*)&Bsb[(c * 16 + lr) * KP + lg * 8];
      acc[c] = __builtin_amdgcn_mfma_f32_16x16x32_bf16(af, bf, acc[c], 0, 0, 0);
    }
  }
#pragma unroll
  for (int c = 0; c < 4; ++c) {
    int col = n0 + c * 16 + lr;
    float bb = bias ? bias[col] : 0.f;
#pragma unroll
    for (int r = 0; r < 4; ++r) {
      int row = m0 + w * 16 + lg * 4 + r;
      float v = acc[c][r] + bb;
      if (RELU) v = fmaxf(v, 0.f);
      C[(long)row * ldc + col] = v;
    }
  }
}

// ---------------------------------------------------------------------------
// Fused flash-style attention (unchanged, validated R6/R8). LDS 48 KiB.
// ---------------------------------------------------------------------------
__global__ __launch_bounds__(256) void attn_k(const float* __restrict__ QKV,
                                              float* __restrict__ O)
{
  const int t = threadIdx.x;
  const int q0 = blockIdx.x * 64;
  const int b = blockIdx.y >> 2, h = blockIdx.y & 3;
  const float* base = QKV + (long)b * 786432;
  const int hc = h * 64;
  __shared__ float Qs[64][64];
  __shared__ float KPs[64][64];
  __shared__ float Vs[64][64];
  const int ldr = t >> 2;
  const int ldc0 = (t & 3) * 16;
  {
    const float* qrow = base + (long)(q0 + ldr) * 768 + hc;
#pragma unroll
    for (int j = 0; j < 16; j += 4) {
      float4 v = *(const float4*)(qrow + ldc0 + j);
      Qs[ldc0 + j + 0][ldr] = v.x; Qs[ldc0 + j + 1][ldr] = v.y;
      Qs[ldc0 + j + 2][ldr] = v.z; Qs[ldc0 + j + 3][ldr] = v.w;
    }
  }
  const int mr = (t >> 4) << 2;
  const int nc = (t & 15) << 2;
  float mrow[4] = {-INFINITY, -INFINITY, -INFINITY, -INFINITY};
  float lrow[4] = {0.f, 0.f, 0.f, 0.f};
  float acc[4][4] = {};
  for (int kt = 0; kt < 16; ++kt) {
    __syncthreads();
    {
      const float* krow = base + (long)(kt * 64 + ldr) * 768 + 256 + hc;
      const float* vrow = base + (long)(kt * 64 + ldr) * 768 + 512 + hc;
#pragma unroll
      for (int j = 0; j < 16; j += 4) {
        float4 kv = *(const float4*)(krow + ldc0 + j);
        KPs[ldc0 + j + 0][ldr] = kv.x; KPs[ldc0 + j + 1][ldr] = kv.y;
        KPs[ldc0 + j + 2][ldr] = kv.z; KPs[ldc0 + j + 3][ldr] = kv.w;
        float4 vv = *(const float4*)(vrow + ldc0 + j);
        *(float4*)&Vs[ldr][ldc0 + j] = vv;
      }
    }
    __syncthreads();
    float s[4][4] = {};
#pragma unroll 8
    for (int d = 0; d < 64; ++d) {
      float4 a = *(const float4*)&Qs[d][mr];
      float4 bv = *(const float4*)&KPs[d][nc];
      s[0][0] += a.x * bv.x; s[0][1] += a.x * bv.y; s[0][2] += a.x * bv.z; s[0][3] += a.x * bv.w;
      s[1][0] += a.y * bv.x; s[1][1] += a.y * bv.y; s[1][2] += a.y * bv.z; s[1][3] += a.y * bv.w;
      s[2][0] += a.z * bv.x; s[2][1] += a.z * bv.y; s[2][2] += a.z * bv.z; s[2][3] += a.z * bv.w;
      s[3][0] += a.w * bv.x; s[3][1] += a.w * bv.y; s[3][2] += a.w * bv.z; s[3][3] += a.w * bv.w;
    }
#pragma unroll
    for (int i = 0; i < 4; ++i) {
#pragma unroll
      for (int j = 0; j < 4; ++j) s[i][j] *= 0.125f;
      float rm = fmaxf(fmaxf(s[i][0], s[i][1]), fmaxf(s[i][2], s[i][3]));
      rm = fmaxf(rm, __shfl_xor(rm, 1));
      rm = fmaxf(rm, __shfl_xor(rm, 2));
      rm = fmaxf(rm, __shfl_xor(rm, 4));
      rm = fmaxf(rm, __shfl_xor(rm, 8));
      float mn = fmaxf(mrow[i], rm);
      float corr = expf(mrow[i] - mn);
      float rs = 0.f;
#pragma unroll
      for (int j = 0; j < 4; ++j) {
        float p = expf(s[i][j] - mn);
        s[i][j] = p; rs += p;
      }
      rs += __shfl_xor(rs, 1);
      rs += __shfl_xor(rs, 2);
      rs += __shfl_xor(rs, 4);
      rs += __shfl_xor(rs, 8);
      lrow[i] = lrow[i] * corr + rs;
      mrow[i] = mn;
#pragma unroll
      for (int j = 0; j < 4; ++j) acc[i][j] *= corr;
    }
    __syncthreads();
#pragma unroll
    for (int i = 0; i < 4; ++i)
#pragma unroll
      for (int j = 0; j < 4; ++j)
        KPs[nc + j][mr + i] = s[i][j];
    __syncthreads();
#pragma unroll 8
    for (int k = 0; k < 64; ++k) {
      float4 p = *(const float4*)&KPs[k][mr];
      float4 v = *(const float4*)&Vs[k][nc];
      acc[0][0] += p.x * v.x; acc[0][1] += p.x * v.y; acc[0][2] += p.x * v.z; acc[0][3] += p.x * v.w;
      acc[1][0] += p.y * v.x; acc[1][1] += p.y * v.y; acc[1][2] += p.y * v.z; acc[1][3] += p.y * v.w;
      acc[2][0] += p.z * v.x; acc[2][1] += p.z * v.y; acc[2][2] += p.z * v.z; acc[2][3] += p.z * v.w;
      acc[3][0] += p.w * v.x; acc[3][1] += p.w * v.y; acc[3][2] += p.w * v.z; acc[3][3] += p.w * v.w;
    }
  }
#pragma unroll
  for (int i = 0; i < 4; ++i) {
    float inv = 1.f / lrow[i];
    float* orow = O + (long)(b * 1024 + q0 + mr + i) * 256 + hc + nc;
    orow[0] = acc[i][0] * inv; orow[1] = acc[i][1] * inv;
    orow[2] = acc[i][2] * inv; orow[3] = acc[i][3] * inv;
  }
}

// ---------------------------------------------------------------------------
// out = LN(x + y) * g + b   (rows of 256, one block per row)
// ---------------------------------------------------------------------------
__global__ __launch_bounds__(256) void resln_k(
    const float* __restrict__ x, const float* __restrict__ y,
    const float* __restrict__ g, const float* __restrict__ be, float* __restrict__ out)
{
  const long row = blockIdx.x;
  const int t = threadIdx.x;
  float v = x[row * 256 + t] + y[row * 256 + t];
  float s = v;
#pragma unroll
  for (int o = 32; o > 0; o >>= 1) s += __shfl_xor(s, o);
  __shared__ float w1r[4];
  __shared__ float w2r[4];
  if ((t & 63) == 0) w1r[t >> 6] = s;
  __syncthreads();
  float mean = (w1r[0] + w1r[1] + w1r[2] + w1r[3]) * (1.f / 256.f);
  float d = v - mean;
  float q = d * d;
#pragma unroll
  for (int o = 32; o > 0; o >>= 1) q += __shfl_xor(q, o);
  if ((t & 63) == 0) w2r[t >> 6] = q;
  __syncthreads();
  float var = (w2r[0] + w2r[1] + w2r[2] + w2r[3]) * (1.f / 256.f);
  out[row * 256 + t] = d * (1.f / sqrtf(var + 1e-5f)) * g[t] + be[t];
}

// ---------------------------------------------------------------------------
// Fused beat encoder v2 (proven R9: 385us, conflicts 25x down).
// ---------------------------------------------------------------------------
__global__ __launch_bounds__(256) void encoder_k(
    const float* __restrict__ beats, const float* __restrict__ rr,
    const float* __restrict__ c1w, const float* __restrict__ c1b,
    const float* __restrict__ c2w, const float* __restrict__ c2b,
    const float* __restrict__ fcw, const float* __restrict__ fcb,
    const float* __restrict__ mtok, const int* __restrict__ nmask,
    const float* __restrict__ vmask,
    float* __restrict__ e, float* __restrict__ em)
{
  const int bn = blockIdx.x;
  const int t = threadIdx.x;
  __shared__ float xin[256];
  __shared__ float o1e[32][64];
  __shared__ float o1o[32][64];
  __shared__ float pooled[66];
  xin[t] = beats[(long)bn * 256 + t];
  __syncthreads();
  for (int r = 0; r < 16; ++r) {
    int idx = t + 256 * r;
    int c = idx >> 7, l = idx & 127;
    int cu = __builtin_amdgcn_readfirstlane(c);
    const float* w = c1w + cu * 5;
    float a = c1b[cu];
    int base = 2 * l - 2;
    if (base >= 0) a += xin[base] * w[0];
    if (base + 1 >= 0) a += xin[base + 1] * w[1];
    a += xin[base + 2] * w[2];
    a += xin[base + 3] * w[3];
    if (base + 4 < 256) a += xin[base + 4] * w[4];
    a = fmaxf(a, 0.f);
    if (l & 1) o1o[c][l >> 1] = a; else o1e[c][l >> 1] = a;
  }
  __syncthreads();
  for (int r = 0; r < 16; ++r) {
    int idx = t + 256 * r;
    int c = idx >> 6, l = idx & 63;
    int cu = __builtin_amdgcn_readfirstlane(c);
    float a = c2b[cu];
    bool hm = (l > 0), hp = (l < 63);
    int lm = hm ? l - 1 : 0;
    int lp = hp ? l + 1 : 63;
    for (int ci = 0; ci < 32; ++ci) {
      const float* w = c2w + (cu * 32 + ci) * 5;
      float w0 = w[0], w1 = w[1], w2v = w[2], w3 = w[3], w4 = w[4];
      float e0 = o1e[ci][l], o0 = o1o[ci][l];
      float emv = o1e[ci][lm], omv = o1o[ci][lm];
      float epv = o1e[ci][lp];
      a += e0 * w2v + o0 * w3;
      if (hm) a += emv * w0 + omv * w1;
      if (hp) a += epv * w4;
    }
    a = fmaxf(a, 0.f);
#pragma unroll
    for (int o = 32; o > 0; o >>= 1) a += __shfl_xor(a, o);
    if ((t & 63) == 0) pooled[cu] = a * (1.f / 64.f);
  }
  if (t == 64) pooled[64] = rr[(long)bn * 2 + 0];
  if (t == 65) pooled[65] = rr[(long)bn * 2 + 1];
  __syncthreads();
  float a = fcb[t];
  for (int k = 0; k < 66; ++k) a += pooled[k] * fcw[t * 66 + k];
  e[(long)bn * 256 + t] = a;
  float mv = nmask[bn] ? mtok[t] : a;
  em[(long)bn * 256 + t] = mv * vmask[bn];
}

// ---------------------------------------------------------------------------
// Top-5 per sim row (ties -> lower index), union band {i-1,i+1}. 2D grid.
// ---------------------------------------------------------------------------
__global__ __launch_bounds__(256) void topk_k(const float* __restrict__ sim,
    int* __restrict__ nbr, float* __restrict__ deg)
{
  const int i = blockIdx.x;
  const int b = blockIdx.y;
  const float* row = sim + (long)b * 1048576 + (long)i * CN;
  const int t = threadIdx.x;
  float v[4]; int id[4];
  float4 rv = ((const float4*)row)[t];
  v[0] = rv.x; v[1] = rv.y; v[2] = rv.z; v[3] = rv.w;
#pragma unroll
  for (int j = 0; j < 4; ++j) id[j] = t * 4 + j;
  __shared__ float vr[256];
  __shared__ int ir[256];
  __shared__ int chosen[CK];
  for (int kk = 0; kk < CK; ++kk) {
    float bv = v[0]; int bi = id[0];
#pragma unroll
    for (int j = 1; j < 4; ++j)
      if (v[j] > bv || (v[j] == bv && id[j] < bi)) { bv = v[j]; bi = id[j]; }
    vr[t] = bv; ir[t] = bi;
    __syncthreads();
    for (int s2 = 128; s2 > 0; s2 >>= 1) {
      if (t < s2) {
        float ov = vr[t + s2]; int oi = ir[t + s2];
        if (ov > vr[t] || (ov == vr[t] && oi < ir[t])) { vr[t] = ov; ir[t] = oi; }
      }
      __syncthreads();
    }
    if (t == 0) chosen[kk] = ir[0];
    __syncthreads();
    int c = chosen[kk];
#pragma unroll
    for (int j = 0; j < 4; ++j) if (id[j] == c) v[j] = -INFINITY;
  }
  if (t == 0) {
    int list[CK + 2]; int cnt = 0;
    for (int kk = 0; kk < CK; ++kk) list[cnt++] = chosen[kk];
    if (i > 0) {
      bool found = false;
      for (int j = 0; j < CK; ++j) if (chosen[j] == i - 1) found = true;
      if (!found) list[cnt++] = i - 1;
    }
    if (i < CN - 1) {
      bool found = false;
      for (int j = 0; j < CK; ++j) if (chosen[j] == i + 1) found = true;
      if (!found) list[cnt++] = i + 1;
    }
    deg[(long)b * CN + i] = (float)cnt;
    for (int j = 0; j < 8; ++j)
      nbr[((long)b * CN + i) * 8 + j] = (j < cnt) ? list[j] : -1;
  }
}

// ---------------------------------------------------------------------------
// Sparse GNN aggregate
// ---------------------------------------------------------------------------
__global__ __launch_bounds__(256) void agg_k(const float* __restrict__ x,
    const int* __restrict__ nbr, const float* __restrict__ deg, float* __restrict__ agg)
{
  const long row = blockIdx.x;
  const int t = threadIdx.x;
  const long bbase = (row >> 10) << 10;
  const int* nb = &nbr[row * 8];
  float s = 0.f;
  for (int j = 0; j < 8; ++j) {
    int n2 = nb[j];
    if (n2 >= 0) s += x[(bbase + n2) * 256 + t];
  }
  agg[row * 256 + t] = s / (deg[row] + 1e-6f);
}

// ---------------------------------------------------------------------------
// Bool-mask upload-layout detection + build.
// ---------------------------------------------------------------------------
__global__ void maskdetect_k(const unsigned char* __restrict__ p, int* __restrict__ flag) {
  int i = blockIdx.x * 256 + threadIdx.x;
  unsigned char c = p[i];
  int f = 0;
  if (c == 0x01) f |= 1;
  if (c == 0x3F || c == 0x80) f |= 2;
  if (c != 0 && (i & 3) == 1) f |= 4;
  if (c != 0 && ((i & 3) == 2 || (i & 3) == 3)) f |= 8;
  if (f) atomicOr(flag, f);
}
__global__ void maskbuild_k(const void* __restrict__ nm, const void* __restrict__ vm,
                            const int* __restrict__ flag, int* __restrict__ outm,
                            float* __restrict__ outv) {
  int i = blockIdx.x * 256 + threadIdx.x;
  int f = *flag;
  int layout;
  if (f & 2) layout = (f & 4) ? 2 : 3;
  else if (f & (4 | 8)) layout = 1;
  else layout = 0;
  bool m, vv;
  if (layout == 1)      { m = ((const unsigned char*)nm)[i] != 0;  vv = ((const unsigned char*)vm)[i] != 0; }
  else if (layout == 0) { m = ((const int*)nm)[i] != 0;            vv = ((const int*)vm)[i] != 0; }
  else if (layout == 2) { m = ((const unsigned short*)nm)[i] != 0; vv = ((const unsigned short*)vm)[i] != 0; }
  else                  { m = ((const unsigned int*)nm)[i] != 0;   vv = ((const unsigned int*)vm)[i] != 0; }
  outm[i] = m ? 1 : 0;
  outv[i] = vv ? 1.f : 0.f;
}

// ---------------------------------------------------------------------------
// Host-side transformer stack. FFN via bf16-MFMA bgemm; full-width when the
// workspace fits an unchunked 4096x2048 hidden (F_Hfull), else 4x1024 chunks.
// ---------------------------------------------------------------------------
static void run_temporal(const float* x0, float* bufX, float* xfinal,
    const float* qkv_w, const float* qkv_b, const float* out_w, const float* out_b,
    const float* ln1g, const float* ln1b, const float* w1, const float* b1,
    const float* w2, const float* b2, const float* ln2g, const float* ln2b,
    float* F_QKV, float* F_H, float* F_Hfull, float* F_O, float* F_T,
    hipStream_t stream)
{
  for (int l = 0; l < CNL; ++l) {
    const float* xs = (l == 0) ? x0 : bufX;
    gemm_k<true, false, false><<<dim3(12, 64, 1), 256, 0, stream>>>(
        xs, 256, 0, 0, qkv_w + (long)l * 768 * 256, 256, 0, 0,
        F_QKV, 768, 0, 0, qkv_b + l * 768, 1.f, 256, 1);
    attn_k<<<dim3(16, 16), 256, 0, stream>>>(F_QKV, F_O);
    gemm_k<true, false, false><<<dim3(4, 64, 1), 256, 0, stream>>>(
        F_O, 256, 0, 0, out_w + (long)l * 65536, 256, 0, 0,
        F_T, 256, 0, 0, out_b + l * 256, 1.f, 256, 1);
    resln_k<<<CBN, 256, 0, stream>>>(xs, F_T, ln1g + l * 256, ln1b + l * 256, bufX);
    if (F_Hfull) {
      bgemm_k<true><<<dim3(32, 64), 256, 0, stream>>>(
          bufX, 256, w1 + (long)l * 2048 * 256, 256, F_Hfull, 2048,
          b1 + l * 2048, 256);
      bgemm_k<false><<<dim3(4, 64), 256, 0, stream>>>(
          F_Hfull, 2048, w2 + (long)l * 2048 * 256, 2048, F_T, 256,
          b2 + l * 256, 2048);
    } else {
      for (int c = 0; c < 4; ++c) {
        const float* xc = bufX + (long)c * 262144;
        bgemm_k<true><<<dim3(32, 16), 256, 0, stream>>>(
            xc, 256, w1 + (long)l * 2048 * 256, 256, F_H, 2048,
            b1 + l * 2048, 256);
        bgemm_k<false><<<dim3(4, 16), 256, 0, stream>>>(
            F_H, 2048, w2 + (long)l * 2048 * 256, 2048, F_T + (long)c * 262144, 256,
            b2 + l * 256, 2048);
      }
    }
    float* dst = (l < CNL - 1) ? bufX : xfinal;
    resln_k<<<CBN, 256, 0, stream>>>(bufX, F_T, ln2g + l * 256, ln2b + l * 256, dst);
  }
}

extern "C" void kernel_launch(void* const* d_in, const int* in_sizes, int n_in,
                              void* d_out, int out_size, void* d_ws, size_t ws_size,
                              hipStream_t stream)
{
  (void)in_sizes; (void)n_in; (void)out_size;
  const float* beats = (const float*)d_in[0];
  const float* rr    = (const float*)d_in[1];
  const void*  nmask = d_in[2];
  const void*  vmask = d_in[3];
  const float* c1w  = (const float*)d_in[4];
  const float* c1b  = (const float*)d_in[5];
  const float* c2w  = (const float*)d_in[6];
  const float* c2b  = (const float*)d_in[7];
  const float* fcw  = (const float*)d_in[8];
  const float* fcb  = (const float*)d_in[9];
  const float* mtok = (const float*)d_in[10];
  const float* qkv_w = (const float*)d_in[11];
  const float* qkv_b = (const float*)d_in[12];
  const float* out_w = (const float*)d_in[13];
  const float* out_b = (const float*)d_in[14];
  const float* ln1g = (const float*)d_in[15];
  const float* ln1b = (const float*)d_in[16];
  const float* w1   = (const float*)d_in[17];
  const float* b1   = (const float*)d_in[18];
  const float* w2   = (const float*)d_in[19];
  const float* b2   = (const float*)d_in[20];
  const float* ln2g = (const float*)d_in[21];
  const float* ln2b = (const float*)d_in[22];
  const float* gsw  = (const float*)d_in[23];
  const float* gsb  = (const float*)d_in[24];
  const float* gnw  = (const float*)d_in[25];
  const float* gnb  = (const float*)d_in[26];
  const float* dcw  = (const float*)d_in[27];
  const float* dcb  = (const float*)d_in[28];
  float* out = (float*)d_out;   // f32 output (reference returns float32)

  float* W = (float*)d_ws;
  const long M1 = 1048576;
  float* F_X   = W + 0 * M1;
  float* F_E   = W + 1 * M1;
  float* F_EM  = W + 2 * M1;
  float* F_QKV = W + 3 * M1;    // 3M; aliased: chunked FFN h (2M), sim (4M w/ F_O)
  float* F_O   = W + 6 * M1;
  float* F_T   = W + 7 * M1;
  float* MISC  = W + 8 * M1;
  float* F_DEG = MISC;
  float* F_VAL = MISC + 4096;
  int*   I_MASK = (int*)(MISC + 8192);
  int*   I_NBR  = I_MASK + 4096;
  int*   I_FLAG = I_NBR + 4096 * 8;
  float* F_H   = F_QKV;          // chunked FFN hidden (1024x2048)
  float* F_SIM = F_QKV;          // batched sim (4x1024x1024, spans F_QKV+F_O)
  float* F_G2  = F_E;
  float* F_AGG = F_EM;
  // unchunked FFN hidden (4096x2048 = 8M floats) if workspace is big enough
  float* F_Hfull = (ws_size >= (size_t)17 * 1048576 * 4) ? (W + 9 * M1) : nullptr;

  // --- masks (layout-detected) ---
  hipMemsetAsync(I_FLAG, 0, 4, stream);
  maskdetect_k<<<16, 256, 0, stream>>>((const unsigned char*)nmask, I_FLAG);
  maskbuild_k<<<16, 256, 0, stream>>>(nmask, vmask, I_FLAG, I_MASK, F_VAL);

  // --- beat encoder -> e, em ---
  encoder_k<<<CBN, 256, 0, stream>>>(beats, rr, c1w, c1b, c2w, c2b, fcw, fcb, mtok,
                                     I_MASK, F_VAL, F_E, F_EM);

  // --- target branch: temporal(e) -> out[0:1M] (f32) ---
  run_temporal(F_E, F_X, out,
      qkv_w, qkv_b, out_w, out_b, ln1g, ln1b, w1, b1, w2, b2, ln2g, ln2b,
      F_QKV, F_H, F_Hfull, F_O, F_T, stream);

  // --- masked branch: temporal(em) -> F_X (f32) ---
  run_temporal(F_EM, F_X, F_X,
      qkv_w, qkv_b, out_w, out_b, ln1g, ln1b, w1, b1, w2, b2, ln2g, ln2b,
      F_QKV, F_H, F_Hfull, F_O, F_T, stream);

  // --- graph build: sim (batched over 4), topk(5) + band; f32 (ranking!) ---
  gemm_k<true, false, false><<<dim3(16, 16, 4), 256, 0, stream>>>(
      F_X, 256, 262144, 0, F_X, 256, 262144, 0,
      F_SIM, 1024, 1048576, 0, nullptr, 1.f, 256, 1);
  topk_k<<<dim3(CN, CB), 256, 0, stream>>>(F_SIM, I_NBR, F_DEG);

  // --- GNN layers ---
  float* cur = F_X; float* oth = F_G2;
  for (int l = 0; l < CGL; ++l) {
    agg_k<<<CBN, 256, 0, stream>>>(cur, I_NBR, F_DEG, F_AGG);
    gemm_k<true, false, false><<<dim3(4, 64, 1), 256, 0, stream>>>(
        cur, 256, 0, 0, gsw + (long)l * 65536, 256, 0, 0,
        oth, 256, 0, 0, gsb + l * 256, 1.f, 256, 1);
    gemm_k<true, false, true><<<dim3(4, 64, 1), 256, 0, stream>>>(
        F_AGG, 256, 0, 0, gnw + (long)l * 65536, 256, 0, 0,
        oth, 256, 0, 0, gnb + l * 256, 1.f, 256, 1);
    float* t2 = cur; cur = oth; oth = t2;
  }

  // --- decoder: recon -> out[1M:2M] (f32) ---
  gemm_k<true, false, false><<<dim3(4, 64, 1), 256, 0, stream>>>(
      cur, 256, 0, 0, dcw, 256, 0, 0, out + M1, 256, 0, 0, dcb, 1.f, 256, 1);
}

// Round 12
// 1298.992 us; speedup vs baseline: 4.1316x; 1.2675x over previous
//
#include <hip/hip_runtime.h>
#include <hip/hip_bf16.h>
#include <math.h>

using bf16 = __hip_bfloat16;

constexpr int CB = 4, CN = 1024, CD = 256, CH = 4, CFF = 2048;
constexpr int CNL = 2, CGL = 3, CK = 5, CBN = CB * CN;

using bfrag = __attribute__((ext_vector_type(8))) short;   // 8 bf16 (4 VGPR)
using ffrag = __attribute__((ext_vector_type(4))) float;   // 4 f32 acc

__device__ __forceinline__ unsigned short f2b(float f) {   // f32->bf16 RNE
  union { float f; unsigned int u; } c; c.f = f;
  unsigned int u = c.u;
  return (unsigned short)((u + 0x7FFF + ((u >> 16) & 1)) >> 16);
}

// ---------------------------------------------------------------------------
// f32 tiled GEMM (kept ONLY for sim: top-k ranking must match f32 reference).
// ---------------------------------------------------------------------------
template<bool TRANSB, bool RELU, bool ACCUM>
__global__ __launch_bounds__(256) void gemm_k(
    const float* __restrict__ A, int lda, long sAb, long sAz,
    const float* __restrict__ Bm, int ldb, long sBb, long sBz,
    float* __restrict__ C, int ldc, long sCb, long sCz,
    const float* __restrict__ bias, float scale, int K, int zdiv)
{
  __shared__ float As[16][64];
  __shared__ float Bs[16][64];
  const int t = threadIdx.x;
  const int z = blockIdx.z;
  const int zb = z / zdiv, zh = z - zb * zdiv;
  const float* Ap = A + (long)zb * sAb + (long)zh * sAz;
  const float* Bp = Bm + (long)zb * sBb + (long)zh * sBz;
  float* Cp = C + (long)zb * sCb + (long)zh * sCz;
  const int m0 = blockIdx.y * 64, n0 = blockIdx.x * 64;
  const int lr = t >> 2;
  const int lk = (t & 3) << 2;
  const int mr = (t >> 4) << 2;
  const int nc = (t & 15) << 2;
  float acc[4][4] = {};
  for (int k0 = 0; k0 < K; k0 += 16) {
    float4 av = *(const float4*)&Ap[(long)(m0 + lr) * lda + k0 + lk];
    As[lk + 0][lr] = av.x; As[lk + 1][lr] = av.y;
    As[lk + 2][lr] = av.z; As[lk + 3][lr] = av.w;
    if (TRANSB) {
      float4 bv = *(const float4*)&Bp[(long)(n0 + lr) * ldb + k0 + lk];
      Bs[lk + 0][lr] = bv.x; Bs[lk + 1][lr] = bv.y;
      Bs[lk + 2][lr] = bv.z; Bs[lk + 3][lr] = bv.w;
    } else {
      const int bk = t >> 4, bn2 = (t & 15) << 2;
      float4 bv = *(const float4*)&Bp[(long)(k0 + bk) * ldb + n0 + bn2];
      Bs[bk][bn2 + 0] = bv.x; Bs[bk][bn2 + 1] = bv.y;
      Bs[bk][bn2 + 2] = bv.z; Bs[bk][bn2 + 3] = bv.w;
    }
    __syncthreads();
#pragma unroll
    for (int k = 0; k < 16; ++k) {
      float4 a = *(const float4*)&As[k][mr];
      float4 b = *(const float4*)&Bs[k][nc];
      acc[0][0] += a.x * b.x; acc[0][1] += a.x * b.y; acc[0][2] += a.x * b.z; acc[0][3] += a.x * b.w;
      acc[1][0] += a.y * b.x; acc[1][1] += a.y * b.y; acc[1][2] += a.y * b.z; acc[1][3] += a.y * b.w;
      acc[2][0] += a.z * b.x; acc[2][1] += a.z * b.y; acc[2][2] += a.z * b.z; acc[2][3] += a.z * b.w;
      acc[3][0] += a.w * b.x; acc[3][1] += a.w * b.y; acc[3][2] += a.w * b.z; acc[3][3] += a.w * b.w;
    }
    __syncthreads();
  }
#pragma unroll
  for (int i = 0; i < 4; ++i) {
    float* crow = Cp + (long)(m0 + mr + i) * ldc + n0 + nc;
#pragma unroll
    for (int j = 0; j < 4; ++j) {
      float v = acc[i][j] * scale;
      if (bias) v += bias[n0 + nc + j];
      if (ACCUM) v += crow[j];
      if (RELU) v = fmaxf(v, 0.f);
      crow[j] = v;
    }
  }
}

// ---------------------------------------------------------------------------
// bf16 MFMA GEMM (R10-verified): C = A*B^T (+bias)(+=C)(relu).
// Tile 64x64, K-step 32, 4 waves. KP=40 (rows hold 32 k-values, max off 39).
// ---------------------------------------------------------------------------
template<bool RELU, bool ACCUM>
__global__ __launch_bounds__(256) void bgemm_k(
    const float* __restrict__ A, int lda,
    const float* __restrict__ Bm, int ldb,
    float* __restrict__ C, int ldc,
    const float* __restrict__ bias, int K)
{
  constexpr int KP = 40;
  __shared__ unsigned short Asb[64 * KP];
  __shared__ unsigned short Bsb[64 * KP];
  const int t = threadIdx.x;
  const int m0 = blockIdx.y * 64, n0 = blockIdx.x * 64;
  const int srow = t >> 2, skk = (t & 3) << 3;
  const int w = t >> 6, l = t & 63;
  const int lr = l & 15, lg = l >> 4;
  ffrag acc[4] = {};
  for (int k0 = 0; k0 < K; k0 += 32) {
    const float* arow = A + (long)(m0 + srow) * lda + k0 + skk;
    const float* brow = Bm + (long)(n0 + srow) * ldb + k0 + skk;
    float4 a1 = *(const float4*)(arow);
    float4 a2 = *(const float4*)(arow + 4);
    float4 b1 = *(const float4*)(brow);
    float4 b2 = *(const float4*)(brow + 4);
    bfrag ap, bp;
    ap[0] = (short)f2b(a1.x); ap[1] = (short)f2b(a1.y);
    ap[2] = (short)f2b(a1.z); ap[3] = (short)f2b(a1.w);
    ap[4] = (short)f2b(a2.x); ap[5] = (short)f2b(a2.y);
    ap[6] = (short)f2b(a2.z); ap[7] = (short)f2b(a2.w);
    bp[0] = (short)f2b(b1.x); bp[1] = (short)f2b(b1.y);
    bp[2] = (short)f2b(b1.z); bp[3] = (short)f2b(b1.w);
    bp[4] = (short)f2b(b2.x); bp[5] = (short)f2b(b2.y);
    bp[6] = (short)f2b(b2.z); bp[7] = (short)f2b(b2.w);
    __syncthreads();
    *(bfrag*)&Asb[srow * KP + skk] = ap;
    *(bfrag*)&Bsb[srow * KP + skk] = bp;
    __syncthreads();
    bfrag af = *(const bfrag*)&Asb[(w * 16 + lr) * KP + lg * 8];
#pragma unroll
    for (int c = 0; c < 4; ++c) {
      bfrag bf = *(const bfrag*)&Bsb[(c * 16 + lr) * KP + lg * 8];
      acc[c] = __builtin_amdgcn_mfma_f32_16x16x32_bf16(af, bf, acc[c], 0, 0, 0);
    }
  }
#pragma unroll
  for (int c = 0; c < 4; ++c) {
    int col = n0 + c * 16 + lr;
    float bb = bias ? bias[col] : 0.f;
#pragma unroll
    for (int r = 0; r < 4; ++r) {
      int row = m0 + w * 16 + lg * 4 + r;
      float v = acc[c][r] + bb;
      if (ACCUM) v += C[(long)row * ldc + col];
      if (RELU) v = fmaxf(v, 0.f);
      C[(long)row * ldc + col] = v;
    }
  }
}

// ---------------------------------------------------------------------------
// MFMA flash attention. R11 BUG FIX: rows here hold the FULL d=64 (not a
// 32-slice like bgemm), so stride must be >=64. KPA=72 (was 40 -> row
// overflow: offsets 40..63 aliased the next row => corrupted tiles, 0.328).
// LDS 4 x 64 x 72 x 2B = 36 KB.
// ---------------------------------------------------------------------------
__global__ __launch_bounds__(256) void attn_k(const float* __restrict__ QKV,
                                              float* __restrict__ O)
{
  constexpr int KPA = 72;
  __shared__ unsigned short Qs[64 * KPA];   // Q[m][d]
  __shared__ unsigned short Ks[64 * KPA];   // K[n][d]
  __shared__ unsigned short Vt[64 * KPA];   // V^T[d][k]
  __shared__ unsigned short Ps[64 * KPA];   // P[m][k]
  const int t = threadIdx.x;
  const int q0 = blockIdx.x * 64;
  const int b = blockIdx.y >> 2, h = blockIdx.y & 3;
  const float* base = QKV + (long)b * 786432;
  const int hc = h * 64;
  const int srow = t >> 2, scol0 = (t & 3) * 16;
  const int w = t >> 6, l = t & 63;
  const int lr = l & 15, lg = l >> 4;
  // stage Q (rows q0..q0+63, cols hc..hc+63) as bf16
  {
    const float* qrow = base + (long)(q0 + srow) * 768 + hc + scol0;
    float4 q1 = *(const float4*)(qrow);
    float4 q2 = *(const float4*)(qrow + 4);
    float4 q3 = *(const float4*)(qrow + 8);
    float4 q4 = *(const float4*)(qrow + 12);
    bfrag qa, qb;
    qa[0] = (short)f2b(q1.x); qa[1] = (short)f2b(q1.y);
    qa[2] = (short)f2b(q1.z); qa[3] = (short)f2b(q1.w);
    qa[4] = (short)f2b(q2.x); qa[5] = (short)f2b(q2.y);
    qa[6] = (short)f2b(q2.z); qa[7] = (short)f2b(q2.w);
    qb[0] = (short)f2b(q3.x); qb[1] = (short)f2b(q3.y);
    qb[2] = (short)f2b(q3.z); qb[3] = (short)f2b(q3.w);
    qb[4] = (short)f2b(q4.x); qb[5] = (short)f2b(q4.y);
    qb[6] = (short)f2b(q4.z); qb[7] = (short)f2b(q4.w);
    *(bfrag*)&Qs[srow * KPA + scol0] = qa;
    *(bfrag*)&Qs[srow * KPA + scol0 + 8] = qb;
  }
  float mrow[4] = {-INFINITY, -INFINITY, -INFINITY, -INFINITY};
  float lrow[4] = {0.f, 0.f, 0.f, 0.f};
  ffrag oacc[4] = {};
  for (int kt = 0; kt < 16; ++kt) {
    __syncthreads();   // prev tile's Ks/Vt/Ps reads complete (Qs on iter 0)
    {
      const float* krow = base + (long)(kt * 64 + srow) * 768 + 256 + hc + scol0;
      float4 k1 = *(const float4*)(krow);
      float4 k2 = *(const float4*)(krow + 4);
      float4 k3 = *(const float4*)(krow + 8);
      float4 k4 = *(const float4*)(krow + 12);
      bfrag ka, kb;
      ka[0] = (short)f2b(k1.x); ka[1] = (short)f2b(k1.y);
      ka[2] = (short)f2b(k1.z); ka[3] = (short)f2b(k1.w);
      ka[4] = (short)f2b(k2.x); ka[5] = (short)f2b(k2.y);
      ka[6] = (short)f2b(k2.z); ka[7] = (short)f2b(k2.w);
      kb[0] = (short)f2b(k3.x); kb[1] = (short)f2b(k3.y);
      kb[2] = (short)f2b(k3.z); kb[3] = (short)f2b(k3.w);
      kb[4] = (short)f2b(k4.x); kb[5] = (short)f2b(k4.y);
      kb[6] = (short)f2b(k4.z); kb[7] = (short)f2b(k4.w);
      *(bfrag*)&Ks[srow * KPA + scol0] = ka;
      *(bfrag*)&Ks[srow * KPA + scol0 + 8] = kb;
      const float* vrow = base + (long)(kt * 64 + srow) * 768 + 512 + hc + scol0;
      float4 v1 = *(const float4*)(vrow);
      float4 v2 = *(const float4*)(vrow + 4);
      float4 v3 = *(const float4*)(vrow + 8);
      float4 v4 = *(const float4*)(vrow + 12);
      float vv[16] = {v1.x, v1.y, v1.z, v1.w, v2.x, v2.y, v2.z, v2.w,
                      v3.x, v3.y, v3.z, v3.w, v4.x, v4.y, v4.z, v4.w};
#pragma unroll
      for (int j = 0; j < 16; ++j)
        Vt[(scol0 + j) * KPA + srow] = f2b(vv[j]);   // V^T[d][k]
    }
    __syncthreads();   // staged tile visible
    // QK^T: S-tile rows [w*16, w*16+16) x 64 cols
    bfrag af0 = *(const bfrag*)&Qs[(w * 16 + lr) * KPA + lg * 8];
    bfrag af1 = *(const bfrag*)&Qs[(w * 16 + lr) * KPA + 32 + lg * 8];
    ffrag sacc[4] = {};
#pragma unroll
    for (int c = 0; c < 4; ++c) {
      bfrag bf0 = *(const bfrag*)&Ks[(c * 16 + lr) * KPA + lg * 8];
      bfrag bf1 = *(const bfrag*)&Ks[(c * 16 + lr) * KPA + 32 + lg * 8];
      sacc[c] = __builtin_amdgcn_mfma_f32_16x16x32_bf16(af0, bf0, sacc[c], 0, 0, 0);
      sacc[c] = __builtin_amdgcn_mfma_f32_16x16x32_bf16(af1, bf1, sacc[c], 0, 0, 0);
    }
    // online softmax; lane owns rows lg*4+r (r=0..3), cols c*16+lr
#pragma unroll
    for (int r = 0; r < 4; ++r) {
      float s0 = sacc[0][r] * 0.125f, s1 = sacc[1][r] * 0.125f;
      float s2 = sacc[2][r] * 0.125f, s3 = sacc[3][r] * 0.125f;
      float rm = fmaxf(fmaxf(s0, s1), fmaxf(s2, s3));
      rm = fmaxf(rm, __shfl_xor(rm, 1));
      rm = fmaxf(rm, __shfl_xor(rm, 2));
      rm = fmaxf(rm, __shfl_xor(rm, 4));
      rm = fmaxf(rm, __shfl_xor(rm, 8));
      float mn = fmaxf(mrow[r], rm);
      float corr = expf(mrow[r] - mn);   // 0 when mrow=-inf
      float p0 = expf(s0 - mn), p1 = expf(s1 - mn);
      float p2 = expf(s2 - mn), p3 = expf(s3 - mn);
      float rs = p0 + p1 + p2 + p3;
      rs += __shfl_xor(rs, 1);
      rs += __shfl_xor(rs, 2);
      rs += __shfl_xor(rs, 4);
      rs += __shfl_xor(rs, 8);
      lrow[r] = lrow[r] * corr + rs;
      mrow[r] = mn;
      oacc[0][r] *= corr; oacc[1][r] *= corr;
      oacc[2][r] *= corr; oacc[3][r] *= corr;
      int prow = (w * 16 + lg * 4 + r) * KPA;
      Ps[prow + 0 * 16 + lr] = f2b(p0);
      Ps[prow + 1 * 16 + lr] = f2b(p1);
      Ps[prow + 2 * 16 + lr] = f2b(p2);
      Ps[prow + 3 * 16 + lr] = f2b(p3);
    }
    __syncthreads();   // Ps visible
    // PV: O rows [w*16, w*16+16) x 64 d-cols
    bfrag pa0 = *(const bfrag*)&Ps[(w * 16 + lr) * KPA + lg * 8];
    bfrag pa1 = *(const bfrag*)&Ps[(w * 16 + lr) * KPA + 32 + lg * 8];
#pragma unroll
    for (int c = 0; c < 4; ++c) {
      bfrag vb0 = *(const bfrag*)&Vt[(c * 16 + lr) * KPA + lg * 8];
      bfrag vb1 = *(const bfrag*)&Vt[(c * 16 + lr) * KPA + 32 + lg * 8];
      oacc[c] = __builtin_amdgcn_mfma_f32_16x16x32_bf16(pa0, vb0, oacc[c], 0, 0, 0);
      oacc[c] = __builtin_amdgcn_mfma_f32_16x16x32_bf16(pa1, vb1, oacc[c], 0, 0, 0);
    }
  }
  float inv[4];
#pragma unroll
  for (int r = 0; r < 4; ++r) inv[r] = 1.f / lrow[r];
#pragma unroll
  for (int c = 0; c < 4; ++c) {
    int col = hc + c * 16 + lr;
#pragma unroll
    for (int r = 0; r < 4; ++r) {
      int row = q0 + w * 16 + lg * 4 + r;
      O[(long)(b * 1024 + row) * 256 + col] = oacc[c][r] * inv[r];
    }
  }
}

// ---------------------------------------------------------------------------
// out = LN(x + y) * g + b   (rows of 256, one block per row)
// ---------------------------------------------------------------------------
__global__ __launch_bounds__(256) void resln_k(
    const float* __restrict__ x, const float* __restrict__ y,
    const float* __restrict__ g, const float* __restrict__ be, float* __restrict__ out)
{
  const long row = blockIdx.x;
  const int t = threadIdx.x;
  float v = x[row * 256 + t] + y[row * 256 + t];
  float s = v;
#pragma unroll
  for (int o = 32; o > 0; o >>= 1) s += __shfl_xor(s, o);
  __shared__ float w1r[4];
  __shared__ float w2r[4];
  if ((t & 63) == 0) w1r[t >> 6] = s;
  __syncthreads();
  float mean = (w1r[0] + w1r[1] + w1r[2] + w1r[3]) * (1.f / 256.f);
  float d = v - mean;
  float q = d * d;
#pragma unroll
  for (int o = 32; o > 0; o >>= 1) q += __shfl_xor(q, o);
  if ((t & 63) == 0) w2r[t >> 6] = q;
  __syncthreads();
  float var = (w2r[0] + w2r[1] + w2r[2] + w2r[3]) * (1.f / 256.f);
  out[row * 256 + t] = d * (1.f / sqrtf(var + 1e-5f)) * g[t] + be[t];
}

// ---------------------------------------------------------------------------
// Fused beat encoder v2 (proven R9/R10: 380us).
// ---------------------------------------------------------------------------
__global__ __launch_bounds__(256) void encoder_k(
    const float* __restrict__ beats, const float* __restrict__ rr,
    const float* __restrict__ c1w, const float* __restrict__ c1b,
    const float* __restrict__ c2w, const float* __restrict__ c2b,
    const float* __restrict__ fcw, const float* __restrict__ fcb,
    const float* __restrict__ mtok, const int* __restrict__ nmask,
    const float* __restrict__ vmask,
    float* __restrict__ e, float* __restrict__ em)
{
  const int bn = blockIdx.x;
  const int t = threadIdx.x;
  __shared__ float xin[256];
  __shared__ float o1e[32][64];
  __shared__ float o1o[32][64];
  __shared__ float pooled[66];
  xin[t] = beats[(long)bn * 256 + t];
  __syncthreads();
  for (int r = 0; r < 16; ++r) {
    int idx = t + 256 * r;
    int c = idx >> 7, l = idx & 127;
    int cu = __builtin_amdgcn_readfirstlane(c);
    const float* w = c1w + cu * 5;
    float a = c1b[cu];
    int base = 2 * l - 2;
    if (base >= 0) a += xin[base] * w[0];
    if (base + 1 >= 0) a += xin[base + 1] * w[1];
    a += xin[base + 2] * w[2];
    a += xin[base + 3] * w[3];
    if (base + 4 < 256) a += xin[base + 4] * w[4];
    a = fmaxf(a, 0.f);
    if (l & 1) o1o[c][l >> 1] = a; else o1e[c][l >> 1] = a;
  }
  __syncthreads();
  for (int r = 0; r < 16; ++r) {
    int idx = t + 256 * r;
    int c = idx >> 6, l = idx & 63;
    int cu = __builtin_amdgcn_readfirstlane(c);
    float a = c2b[cu];
    bool hm = (l > 0), hp = (l < 63);
    int lm = hm ? l - 1 : 0;
    int lp = hp ? l + 1 : 63;
    for (int ci = 0; ci < 32; ++ci) {
      const float* w = c2w + (cu * 32 + ci) * 5;
      float w0 = w[0], w1 = w[1], w2v = w[2], w3 = w[3], w4 = w[4];
      float e0 = o1e[ci][l], o0 = o1o[ci][l];
      float emv = o1e[ci][lm], omv = o1o[ci][lm];
      float epv = o1e[ci][lp];
      a += e0 * w2v + o0 * w3;
      if (hm) a += emv * w0 + omv * w1;
      if (hp) a += epv * w4;
    }
    a = fmaxf(a, 0.f);
#pragma unroll
    for (int o = 32; o > 0; o >>= 1) a += __shfl_xor(a, o);
    if ((t & 63) == 0) pooled[cu] = a * (1.f / 64.f);
  }
  if (t == 64) pooled[64] = rr[(long)bn * 2 + 0];
  if (t == 65) pooled[65] = rr[(long)bn * 2 + 1];
  __syncthreads();
  float a = fcb[t];
  for (int k = 0; k < 66; ++k) a += pooled[k] * fcw[t * 66 + k];
  e[(long)bn * 256 + t] = a;
  float mv = nmask[bn] ? mtok[t] : a;
  em[(long)bn * 256 + t] = mv * vmask[bn];
}

// ---------------------------------------------------------------------------
// Top-5 per sim row (ties -> lower index), union band {i-1,i+1}. 2D grid.
// ---------------------------------------------------------------------------
__global__ __launch_bounds__(256) void topk_k(const float* __restrict__ sim,
    int* __restrict__ nbr, float* __restrict__ deg)
{
  const int i = blockIdx.x;
  const int b = blockIdx.y;
  const float* row = sim + (long)b * 1048576 + (long)i * CN;
  const int t = threadIdx.x;
  float v[4]; int id[4];
  float4 rv = ((const float4*)row)[t];
  v[0] = rv.x; v[1] = rv.y; v[2] = rv.z; v[3] = rv.w;
#pragma unroll
  for (int j = 0; j < 4; ++j) id[j] = t * 4 + j;
  __shared__ float vr[256];
  __shared__ int ir[256];
  __shared__ int chosen[CK];
  for (int kk = 0; kk < CK; ++kk) {
    float bv = v[0]; int bi = id[0];
#pragma unroll
    for (int j = 1; j < 4; ++j)
      if (v[j] > bv || (v[j] == bv && id[j] < bi)) { bv = v[j]; bi = id[j]; }
    vr[t] = bv; ir[t] = bi;
    __syncthreads();
    for (int s2 = 128; s2 > 0; s2 >>= 1) {
      if (t < s2) {
        float ov = vr[t + s2]; int oi = ir[t + s2];
        if (ov > vr[t] || (ov == vr[t] && oi < ir[t])) { vr[t] = ov; ir[t] = oi; }
      }
      __syncthreads();
    }
    if (t == 0) chosen[kk] = ir[0];
    __syncthreads();
    int c = chosen[kk];
#pragma unroll
    for (int j = 0; j < 4; ++j) if (id[j] == c) v[j] = -INFINITY;
  }
  if (t == 0) {
    int list[CK + 2]; int cnt = 0;
    for (int kk = 0; kk < CK; ++kk) list[cnt++] = chosen[kk];
    if (i > 0) {
      bool found = false;
      for (int j = 0; j < CK; ++j) if (chosen[j] == i - 1) found = true;
      if (!found) list[cnt++] = i - 1;
    }
    if (i < CN - 1) {
      bool found = false;
      for (int j = 0; j < CK; ++j) if (chosen[j] == i + 1) found = true;
      if (!found) list[cnt++] = i + 1;
    }
    deg[(long)b * CN + i] = (float)cnt;
    for (int j = 0; j < 8; ++j)
      nbr[((long)b * CN + i) * 8 + j] = (j < cnt) ? list[j] : -1;
  }
}

// ---------------------------------------------------------------------------
// Sparse GNN aggregate
// ---------------------------------------------------------------------------
__global__ __launch_bounds__(256) void agg_k(const float* __restrict__ x,
    const int* __restrict__ nbr, const float* __restrict__ deg, float* __restrict__ agg)
{
  const long row = blockIdx.x;
  const int t = threadIdx.x;
  const long bbase = (row >> 10) << 10;
  const int* nb = &nbr[row * 8];
  float s = 0.f;
  for (int j = 0; j < 8; ++j) {
    int n2 = nb[j];
    if (n2 >= 0) s += x[(bbase + n2) * 256 + t];
  }
  agg[row * 256 + t] = s / (deg[row] + 1e-6f);
}

// ---------------------------------------------------------------------------
// Bool-mask upload-layout detection + build.
// ---------------------------------------------------------------------------
__global__ void maskdetect_k(const unsigned char* __restrict__ p, int* __restrict__ flag) {
  int i = blockIdx.x * 256 + threadIdx.x;
  unsigned char c = p[i];
  int f = 0;
  if (c == 0x01) f |= 1;
  if (c == 0x3F || c == 0x80) f |= 2;
  if (c != 0 && (i & 3) == 1) f |= 4;
  if (c != 0 && ((i & 3) == 2 || (i & 3) == 3)) f |= 8;
  if (f) atomicOr(flag, f);
}
__global__ void maskbuild_k(const void* __restrict__ nm, const void* __restrict__ vm,
                            const int* __restrict__ flag, int* __restrict__ outm,
                            float* __restrict__ outv) {
  int i = blockIdx.x * 256 + threadIdx.x;
  int f = *flag;
  int layout;
  if (f & 2) layout = (f & 4) ? 2 : 3;
  else if (f & (4 | 8)) layout = 1;
  else layout = 0;
  bool m, vv;
  if (layout == 1)      { m = ((const unsigned char*)nm)[i] != 0;  vv = ((const unsigned char*)vm)[i] != 0; }
  else if (layout == 0) { m = ((const int*)nm)[i] != 0;            vv = ((const int*)vm)[i] != 0; }
  else if (layout == 2) { m = ((const unsigned short*)nm)[i] != 0; vv = ((const unsigned short*)vm)[i] != 0; }
  else                  { m = ((const unsigned int*)nm)[i] != 0;   vv = ((const unsigned int*)vm)[i] != 0; }
  outm[i] = m ? 1 : 0;
  outv[i] = vv ? 1.f : 0.f;
}

// ---------------------------------------------------------------------------
// Host-side transformer stack, all dense GEMMs on MFMA.
// ---------------------------------------------------------------------------
static void run_temporal(const float* x0, float* bufX, float* xfinal,
    const float* qkv_w, const float* qkv_b, const float* out_w, const float* out_b,
    const float* ln1g, const float* ln1b, const float* w1, const float* b1,
    const float* w2, const float* b2, const float* ln2g, const float* ln2b,
    float* F_QKV, float* F_H, float* F_Hfull, float* F_O, float* F_T,
    hipStream_t stream)
{
  for (int l = 0; l < CNL; ++l) {
    const float* xs = (l == 0) ? x0 : bufX;
    bgemm_k<false, false><<<dim3(12, 64), 256, 0, stream>>>(
        xs, 256, qkv_w + (long)l * 768 * 256, 256, F_QKV, 768,
        qkv_b + l * 768, 256);
    attn_k<<<dim3(16, 16), 256, 0, stream>>>(F_QKV, F_O);
    bgemm_k<false, false><<<dim3(4, 64), 256, 0, stream>>>(
        F_O, 256, out_w + (long)l * 65536, 256, F_T, 256,
        out_b + l * 256, 256);
    resln_k<<<CBN, 256, 0, stream>>>(xs, F_T, ln1g + l * 256, ln1b + l * 256, bufX);
    if (F_Hfull) {
      bgemm_k<true, false><<<dim3(32, 64), 256, 0, stream>>>(
          bufX, 256, w1 + (long)l * 2048 * 256, 256, F_Hfull, 2048,
          b1 + l * 2048, 256);
      bgemm_k<false, false><<<dim3(4, 64), 256, 0, stream>>>(
          F_Hfull, 2048, w2 + (long)l * 2048 * 256, 2048, F_T, 256,
          b2 + l * 256, 2048);
    } else {
      for (int c = 0; c < 4; ++c) {
        const float* xc = bufX + (long)c * 262144;
        bgemm_k<true, false><<<dim3(32, 16), 256, 0, stream>>>(
            xc, 256, w1 + (long)l * 2048 * 256, 256, F_H, 2048,
            b1 + l * 2048, 256);
        bgemm_k<false, false><<<dim3(4, 16), 256, 0, stream>>>(
            F_H, 2048, w2 + (long)l * 2048 * 256, 2048, F_T + (long)c * 262144, 256,
            b2 + l * 256, 2048);
      }
    }
    float* dst = (l < CNL - 1) ? bufX : xfinal;
    resln_k<<<CBN, 256, 0, stream>>>(bufX, F_T, ln2g + l * 256, ln2b + l * 256, dst);
  }
}

extern "C" void kernel_launch(void* const* d_in, const int* in_sizes, int n_in,
                              void* d_out, int out_size, void* d_ws, size_t ws_size,
                              hipStream_t stream)
{
  (void)in_sizes; (void)n_in; (void)out_size;
  const float* beats = (const float*)d_in[0];
  const float* rr    = (const float*)d_in[1];
  const void*  nmask = d_in[2];
  const void*  vmask = d_in[3];
  const float* c1w  = (const float*)d_in[4];
  const float* c1b  = (const float*)d_in[5];
  const float* c2w  = (const float*)d_in[6];
  const float* c2b  = (const float*)d_in[7];
  const float* fcw  = (const float*)d_in[8];
  const float* fcb  = (const float*)d_in[9];
  const float* mtok = (const float*)d_in[10];
  const float* qkv_w = (const float*)d_in[11];
  const float* qkv_b = (const float*)d_in[12];
  const float* out_w = (const float*)d_in[13];
  const float* out_b = (const float*)d_in[14];
  const float* ln1g = (const float*)d_in[15];
  const float* ln1b = (const float*)d_in[16];
  const float* w1   = (const float*)d_in[17];
  const float* b1   = (const float*)d_in[18];
  const float* w2   = (const float*)d_in[19];
  const float* b2   = (const float*)d_in[20];
  const float* ln2g = (const float*)d_in[21];
  const float* ln2b = (const float*)d_in[22];
  const float* gsw  = (const float*)d_in[23];
  const float* gsb  = (const float*)d_in[24];
  const float* gnw  = (const float*)d_in[25];
  const float* gnb  = (const float*)d_in[26];
  const float* dcw  = (const float*)d_in[27];
  const float* dcb  = (const float*)d_in[28];
  float* out = (float*)d_out;   // f32 output (reference returns float32)

  float* W = (float*)d_ws;
  const long M1 = 1048576;
  float* F_X   = W + 0 * M1;
  float* F_E   = W + 1 * M1;
  float* F_EM  = W + 2 * M1;
  float* F_QKV = W + 3 * M1;    // 3M; aliased: chunked FFN h (2M), sim (4M w/ F_O)
  float* F_O   = W + 6 * M1;
  float* F_T   = W + 7 * M1;
  float* MISC  = W + 8 * M1;
  float* F_DEG = MISC;
  float* F_VAL = MISC + 4096;
  int*   I_MASK = (int*)(MISC + 8192);
  int*   I_NBR  = I_MASK + 4096;
  int*   I_FLAG = I_NBR + 4096 * 8;
  float* F_H   = F_QKV;          // chunked FFN hidden (1024x2048)
  float* F_SIM = F_QKV;          // batched sim (4x1024x1024, spans F_QKV+F_O)
  float* F_G2  = F_E;
  float* F_AGG = F_EM;
  float* F_Hfull = (ws_size >= (size_t)17 * 1048576 * 4) ? (W + 9 * M1) : nullptr;

  // --- masks (layout-detected) ---
  hipMemsetAsync(I_FLAG, 0, 4, stream);
  maskdetect_k<<<16, 256, 0, stream>>>((const unsigned char*)nmask, I_FLAG);
  maskbuild_k<<<16, 256, 0, stream>>>(nmask, vmask, I_FLAG, I_MASK, F_VAL);

  // --- beat encoder -> e, em ---
  encoder_k<<<CBN, 256, 0, stream>>>(beats, rr, c1w, c1b, c2w, c2b, fcw, fcb, mtok,
                                     I_MASK, F_VAL, F_E, F_EM);

  // --- target branch: temporal(e) -> out[0:1M] (f32) ---
  run_temporal(F_E, F_X, out,
      qkv_w, qkv_b, out_w, out_b, ln1g, ln1b, w1, b1, w2, b2, ln2g, ln2b,
      F_QKV, F_H, F_Hfull, F_O, F_T, stream);

  // --- masked branch: temporal(em) -> F_X (f32) ---
  run_temporal(F_EM, F_X, F_X,
      qkv_w, qkv_b, out_w, out_b, ln1g, ln1b, w1, b1, w2, b2, ln2g, ln2b,
      F_QKV, F_H, F_Hfull, F_O, F_T, stream);

  // --- graph build: sim (f32 — topk ranking must match f32 ref), topk ---
  gemm_k<true, false, false><<<dim3(16, 16, 4), 256, 0, stream>>>(
      F_X, 256, 262144, 0, F_X, 256, 262144, 0,
      F_SIM, 1024, 1048576, 0, nullptr, 1.f, 256, 1);
  topk_k<<<dim3(CN, CB), 256, 0, stream>>>(F_SIM, I_NBR, F_DEG);

  // --- GNN layers (MFMA) ---
  float* cur = F_X; float* oth = F_G2;
  for (int l = 0; l < CGL; ++l) {
    agg_k<<<CBN, 256, 0, stream>>>(cur, I_NBR, F_DEG, F_AGG);
    bgemm_k<false, false><<<dim3(4, 64), 256, 0, stream>>>(
        cur, 256, gsw + (long)l * 65536, 256, oth, 256, gsb + l * 256, 256);
    bgemm_k<false, true><<<dim3(4, 64), 256, 0, stream>>>(
        F_AGG, 256, gnw + (long)l * 65536, 256, oth, 256, gnb + l * 256, 256);
    float* t2 = cur; cur = oth; oth = t2;
  }

  // --- decoder: recon -> out[1M:2M] (f32, MFMA) ---
  bgemm_k<false, false><<<dim3(4, 64), 256, 0, stream>>>(
      cur, 256, dcw, 256, out + M1, 256, dcb, 256);
}